// Round 5
// baseline (341.946 us; speedup 1.0000x reference)
//
#include <hip/hip_runtime.h>
#include <hip/hip_bf16.h>

#define DIM  1024
#define RANK 32
#define BATCH 4
#define SEQ  4096
#define MTOT (BATCH * SEQ)   // 16384

typedef short bf16x8 __attribute__((ext_vector_type(8)));          // MFMA A/B frag (8 bf16)
typedef float f32x4 __attribute__((ext_vector_type(4)));           // 16x16 MFMA C/D frag
typedef float f32x16 __attribute__((ext_vector_type(16)));         // 32x32 MFMA C/D frag
typedef unsigned short ushort8v __attribute__((ext_vector_type(8)));
typedef unsigned int uint2v __attribute__((ext_vector_type(2)));

__device__ inline unsigned short f2bf(float f) {
    union { float f; unsigned int u; } v; v.f = f;
    return (unsigned short)((v.u + 0x7FFFu + ((v.u >> 16) & 1u)) >> 16);  // RNE
}

__device__ inline unsigned int pk_bf16(float a, float b) {
    __hip_bfloat162 h = __float22bfloat162_rn(make_float2(a, b));
    unsigned int u; __builtin_memcpy(&u, &h, 4);
    return u;
}

// async global->LDS, 16B per lane; data lands at lds_base + lane*16 (wave-uniform base)
__device__ inline void gl_lds16(const unsigned short* g, unsigned short* l) {
    __builtin_amdgcn_global_load_lds(
        (const __attribute__((address_space(1))) unsigned int*)g,
        (__attribute__((address_space(3))) unsigned int*)l, 16, 0, 0);
}

// ---------------- K0: pack Q*SC, K (fp32 32x1024 each) -> wqk bf16 (64x1024) -----------
__global__ __launch_bounds__(256) void k_cvt_qk(const float* __restrict__ Q,
                                                const float* __restrict__ K,
                                                unsigned short* __restrict__ wqk) {
    int i = blockIdx.x * 256 + threadIdx.x;        // 65536 total
    int row = i >> 10, col = i & 1023;
    const float SC = 0.045084220027779984f;        // 1/(32*ln2)
    float v = (row < RANK) ? Q[row * DIM + col] * SC : K[(row - RANK) * DIM + col];
    wqk[i] = f2bf(v);
}

// ---------------- K1: tiled transpose + fp32->bf16 (VO -> vot[e][d]) -------------------
__global__ __launch_bounds__(256) void k_transpose_cvt(const float* __restrict__ in,
                                                       unsigned short* __restrict__ out,
                                                       int R, int C) {
    __shared__ float tile[64][65];
    const int tid = threadIdx.x;
    const int c0 = blockIdx.x * 64, r0 = blockIdx.y * 64;
    {
        int c = (tid & 15) * 4;
#pragma unroll
        for (int i = 0; i < 4; ++i) {
            int r = (tid >> 4) + i * 16;
            f32x4 v = *(const f32x4*)(in + (size_t)(r0 + r) * C + c0 + c);
            tile[r][c + 0] = v[0]; tile[r][c + 1] = v[1];
            tile[r][c + 2] = v[2]; tile[r][c + 3] = v[3];
        }
    }
    __syncthreads();
    {
        int r = (tid & 15) * 4;
#pragma unroll
        for (int i = 0; i < 4; ++i) {
            int c = (tid >> 4) + i * 16;
            unsigned short o0 = f2bf(tile[r + 0][c]), o1 = f2bf(tile[r + 1][c]);
            unsigned short o2 = f2bf(tile[r + 2][c]), o3 = f2bf(tile[r + 3][c]);
            unsigned short* p = out + (size_t)(c0 + c) * R + r0 + r;
            p[0] = o0; p[1] = o1; p[2] = o2; p[3] = o3;
        }
    }
}

// ---------------- K2: x fp32 -> xbf bf16, row-major passthrough ------------------------
__global__ __launch_bounds__(256) void k_xbf(const float* __restrict__ x,
                                             unsigned short* __restrict__ xbf) {
    size_t i = ((size_t)blockIdx.x * 256 + threadIdx.x) * 8;
    f32x4 v0 = *(const f32x4*)(x + i);
    f32x4 v1 = *(const f32x4*)(x + i + 4);
    ushort8v o;
    o[0] = f2bf(v0[0]); o[1] = f2bf(v0[1]); o[2] = f2bf(v0[2]); o[3] = f2bf(v0[3]);
    o[4] = f2bf(v1[0]); o[5] = f2bf(v1[1]); o[6] = f2bf(v1[2]); o[7] = f2bf(v1[3]);
    *(ushort8v*)(xbf + i) = o;
}

// ---------------- K3: xqk = xbf @ wqk^T  (M=16384, N=64, K=1024), bf16 out -------------
__global__ __launch_bounds__(256) void k_proj(const unsigned short* __restrict__ xbf,
                                              const unsigned short* __restrict__ wqk,
                                              unsigned short* __restrict__ xqk) {
    __shared__ __align__(16) unsigned short a_lds[128 * 32];
    __shared__ __align__(16) unsigned short w_lds[64 * 32];
    const int tid = threadIdx.x;
    const int w = tid >> 6, lane = tid & 63, l15 = lane & 15, quad = lane >> 4;
    const int wm = w & 1, wn = w >> 1;
    const int rowbase = blockIdx.x * 128;

    f32x4 acc[4][2];
#pragma unroll
    for (int mt = 0; mt < 4; ++mt)
#pragma unroll
        for (int nt = 0; nt < 2; ++nt) acc[mt][nt] = (f32x4){0.f, 0.f, 0.f, 0.f};

    const unsigned short* Ab = xbf + (size_t)(rowbase + w * 32 + (lane >> 2)) * DIM + (lane & 3) * 8;
    const unsigned short* Wb = wqk + (size_t)(w * 16 + (lane >> 2)) * DIM + (lane & 3) * 8;

    for (int k0 = 0; k0 < DIM; k0 += 32) {
        gl_lds16(Ab + k0, &a_lds[(w * 32) * 32]);
        gl_lds16(Ab + (size_t)16 * DIM + k0, &a_lds[(w * 32 + 16) * 32]);
        gl_lds16(Wb + k0, &w_lds[(w * 16) * 32]);
        __syncthreads();
        bf16x8 am[4], bn[2];
#pragma unroll
        for (int mt = 0; mt < 4; ++mt)
            am[mt] = *(const bf16x8*)&a_lds[(wm * 64 + mt * 16 + l15) * 32 + quad * 8];
#pragma unroll
        for (int nt = 0; nt < 2; ++nt)
            bn[nt] = *(const bf16x8*)&w_lds[(wn * 32 + nt * 16 + l15) * 32 + quad * 8];
#pragma unroll
        for (int mt = 0; mt < 4; ++mt)
#pragma unroll
            for (int nt = 0; nt < 2; ++nt)
                acc[mt][nt] = __builtin_amdgcn_mfma_f32_16x16x32_bf16(am[mt], bn[nt], acc[mt][nt], 0, 0, 0);
        __syncthreads();
    }
#pragma unroll
    for (int mt = 0; mt < 4; ++mt)
#pragma unroll
        for (int nt = 0; nt < 2; ++nt)
#pragma unroll
            for (int r = 0; r < 4; ++r) {
                int grow = rowbase + wm * 64 + mt * 16 + quad * 4 + r;
                xqk[(size_t)grow * 64 + wn * 32 + nt * 16 + l15] = f2bf(acc[mt][nt][r]);
            }
}

// ---------------- K5 (round-0): xvoT[b][e][u] = (x @ VO)^T. 128e x 256u, BK=64 ---------
// Proven single-buffer 2-barrier structure, 48 KB LDS, 2 blocks/CU.
// XOR chunk swizzle: staged slot s holds global chunk s^(row&7); frag read uses
// slot (ks*2+half)^(l31&7) -> conflict-free b128 (8 bank-cycles).
__global__ __launch_bounds__(512, 4) void k_xvo(const unsigned short* __restrict__ vot,
                                                const unsigned short* __restrict__ xbf,
                                                unsigned short* __restrict__ xvoT) {
    __shared__ __align__(16) unsigned short a_lds[128 * 64];   // 128 e-rows x 128B
    __shared__ __align__(16) unsigned short b_lds[256 * 64];   // 256 u-rows x 128B
    const int tid = threadIdx.x;
    const int w = tid >> 6, lane = tid & 63, l31 = lane & 31, half = lane >> 5;
    const int wm = w & 1, wn = w >> 1;
    const int ubase = blockIdx.x * 256;
    const int ebase = blockIdx.y * 128;
    const int b = blockIdx.z;

    f32x16 acc[2][2];
#pragma unroll
    for (int at = 0; at < 2; ++at)
#pragma unroll
        for (int bt = 0; bt < 2; ++bt)
#pragma unroll
            for (int i = 0; i < 16; ++i) acc[at][bt][i] = 0.f;

    const int sub = lane >> 3;                 // 0..7 rows within a stage call
    const int g = (lane & 7) ^ (sub & 7);      // swizzled global chunk for this lane
    const int Ra = w * 16 + sub;               // A rows (c adds 8; &7 invariant)
    const int Rb = w * 32 + sub;               // B rows (c adds 8)
    const unsigned short* Ap = vot + (size_t)(ebase + Ra) * DIM + g * 8;
    const unsigned short* Bp = xbf + (size_t)(b * SEQ + ubase + Rb) * DIM + g * 8;

    for (int k0 = 0; k0 < DIM; k0 += 64) {
#pragma unroll
        for (int c = 0; c < 2; ++c)
            gl_lds16(Ap + (size_t)(c * 8) * DIM + k0, &a_lds[(w * 16 + c * 8) * 64]);
#pragma unroll
        for (int c = 0; c < 4; ++c)
            gl_lds16(Bp + (size_t)(c * 8) * DIM + k0, &b_lds[(w * 32 + c * 8) * 64]);
        __syncthreads();

        const int abase = (wm * 64 + l31) * 64;
        const int bbase = (wn * 64 + l31) * 64;
#pragma unroll
        for (int ks = 0; ks < 4; ++ks) {
            const int soff = ((ks * 2 + half) ^ (l31 & 7)) * 8;
            bf16x8 a0 = *(const bf16x8*)&a_lds[abase + soff];
            bf16x8 a1 = *(const bf16x8*)&a_lds[abase + 2048 + soff];
            bf16x8 b0 = *(const bf16x8*)&b_lds[bbase + soff];
            bf16x8 b1 = *(const bf16x8*)&b_lds[bbase + 2048 + soff];
            acc[0][0] = __builtin_amdgcn_mfma_f32_32x32x16_bf16(a0, b0, acc[0][0], 0, 0, 0);
            acc[0][1] = __builtin_amdgcn_mfma_f32_32x32x16_bf16(a0, b1, acc[0][1], 0, 0, 0);
            acc[1][0] = __builtin_amdgcn_mfma_f32_32x32x16_bf16(a1, b0, acc[1][0], 0, 0, 0);
            acc[1][1] = __builtin_amdgcn_mfma_f32_32x32x16_bf16(a1, b1, acc[1][1], 0, 0, 0);
        }
        __syncthreads();
    }
#pragma unroll
    for (int at = 0; at < 2; ++at)
#pragma unroll
        for (int bt = 0; bt < 2; ++bt)
#pragma unroll
            for (int reg = 0; reg < 16; ++reg) {
                int lr = wm * 64 + at * 32 + (reg & 3) + 8 * (reg >> 2) + 4 * half;
                int u = ubase + wn * 64 + bt * 32 + l31;
                xvoT[(size_t)(b * DIM + ebase + lr) * SEQ + u] = f2bf(acc[at][bt][reg]);
            }
}

// ---------------- K6 v7 (FUSED, addr-fixed): out = softmax-PV without materializing P --
// Identical to v6 except the xq fragment address: rowbase is ALREADY a global row
// (0..16383, includes batch) -> xqp must NOT add b*SEQ again. v6 added it, so batches
// 1..3 read past xqk into xbf (absmax 4.87). xkp/Bp keep b-offsets (their row indices
// are per-batch). All layout/sync logic unchanged from v6 (audited element-wise).
__global__ __launch_bounds__(512, 4) void k_spv(const unsigned short* __restrict__ xqk,
                                                const unsigned short* __restrict__ xvoT,
                                                float* __restrict__ out) {
    __shared__ __align__(16) unsigned short p_lds[128 * 64];   // 16 KB P tile (XOR-swz)
    __shared__ __align__(16) unsigned short b_lds[256 * 64];   // 32 KB xvoT tile
    __shared__ float denp[8][32];
    __shared__ float rden[128];
    const int tid = threadIdx.x;
    const int w = tid >> 6, lane = tid & 63, l31 = lane & 31, half = lane >> 5;
    const int wm = w & 1, wn = w >> 1;      // PV decomposition (2M x 4N)
    const int uu = w & 1, qq = w >> 1;      // score decomposition

    const int p = blockIdx.x;
    const int xcd = p & 7, t0 = p >> 3;
    const int rowtile = xcd * 16 + (t0 >> 2);   // 0..127
    const int etile = t0 & 3;                   // 0..3
    const int rowbase = rowtile * 128;          // GLOBAL q-row (includes batch)
    const int ebase = etile * 256;
    const int b = rowbase >> 12;

    // xq fragments (persistent B-operand): global rows rowbase + qq*32 + l31 (NO b*SEQ!)
    const unsigned short* xqp = xqk + (size_t)(rowbase + qq * 32 + l31) * 64 + half * 8;
    const bf16x8 bq0 = *(const bf16x8*)(xqp);
    const bf16x8 bq1 = *(const bf16x8*)(xqp + 16);

    // xk fragment base (A-operand rows = u, PER-BATCH -> needs b*SEQ); tile t adds t*4096
    const unsigned short* xkp = xqk + (size_t)(b * SEQ + uu * 32 + l31) * 64 + 32 + half * 8;

    f32x16 acc[2][2];
#pragma unroll
    for (int at = 0; at < 2; ++at)
#pragma unroll
        for (int bt = 0; bt < 2; ++bt)
#pragma unroll
            for (int i = 0; i < 16; ++i) acc[at][bt][i] = 0.f;

    const int sub = lane >> 3;
    const int g8 = (lane & 7) ^ (sub & 7);
    const unsigned short* Bp = xvoT + (size_t)(b * DIM + ebase + w * 32 + sub) * SEQ + g8 * 8;
    auto stageB = [&](int k0) {
#pragma unroll
        for (int c = 0; c < 4; ++c)
            gl_lds16(Bp + (size_t)(c * 8) * SEQ + k0, &b_lds[(w * 32 + c * 8) * 64]);
    };

    const int NT = SEQ / 64;                    // 64
    float dacc = 0.f;
    const int pbase = (qq * 32 + l31) * 64 + half * 4;   // p_lds write base (ushort units)

    stageB(0);
    bf16x8 kA0 = *(const bf16x8*)(xkp);
    bf16x8 kA1 = *(const bf16x8*)(xkp + 16);
    bf16x8 kB0, kB1;

    for (int t = 0; t < NT; ++t) {
        // ---- score phase: S^T for u-tile t (2 MFMA, K=32) ----
        f32x16 sc;
#pragma unroll
        for (int i = 0; i < 16; ++i) sc[i] = 0.f;
        sc = __builtin_amdgcn_mfma_f32_32x32x16_bf16(kA0, bq0, sc, 0, 0, 0);
        sc = __builtin_amdgcn_mfma_f32_32x32x16_bf16(kA1, bq1, sc, 0, 0, 0);
#pragma unroll
        for (int g = 0; g < 4; ++g) {
            float e0 = exp2f(sc[4 * g + 0]), e1 = exp2f(sc[4 * g + 1]);
            float e2 = exp2f(sc[4 * g + 2]), e3 = exp2f(sc[4 * g + 3]);
            dacc += (e0 + e1) + (e2 + e3);
            uint2v dw; dw[0] = pk_bf16(e0, e1); dw[1] = pk_bf16(e2, e3);
            // chunk = uu*4+g at row q -> slot = chunk^(q&7); q&7 == l31&7
            *(uint2v*)&p_lds[pbase + (((uu * 4 + g) ^ (l31 & 7)) * 8)] = dw;
        }
        asm volatile("s_waitcnt lgkmcnt(0)" ::: "memory");   // p_lds writes done
        asm volatile("s_waitcnt vmcnt(0)" ::: "memory");     // my B(t) rows landed
        __builtin_amdgcn_s_barrier();                        // barrier A: publish p_lds+B
        asm volatile("" ::: "memory");

        // prefetch next xk frags during PV (consumed by next score; data-dep wait there)
        {
            const unsigned short* nx = xkp + (size_t)((t + 1 < NT) ? (t + 1) : t) * 4096;
            kB0 = *(const bf16x8*)(nx);
            kB1 = *(const bf16x8*)(nx + 16);
        }

        // ---- PV phase (round-0 k_pv pattern) ----
        const int abase = (wm * 64 + l31) * 64;
        const int bbase = (wn * 64 + l31) * 64;
        __builtin_amdgcn_s_setprio(1);
#pragma unroll
        for (int ks = 0; ks < 4; ++ks) {
            const int soff = ((ks * 2 + half) ^ (l31 & 7)) * 8;
            bf16x8 a0 = *(const bf16x8*)&p_lds[abase + soff];
            bf16x8 a1 = *(const bf16x8*)&p_lds[abase + 2048 + soff];
            bf16x8 b0 = *(const bf16x8*)&b_lds[bbase + soff];
            bf16x8 b1 = *(const bf16x8*)&b_lds[bbase + 2048 + soff];
            acc[0][0] = __builtin_amdgcn_mfma_f32_32x32x16_bf16(a0, b0, acc[0][0], 0, 0, 0);
            acc[0][1] = __builtin_amdgcn_mfma_f32_32x32x16_bf16(a0, b1, acc[0][1], 0, 0, 0);
            acc[1][0] = __builtin_amdgcn_mfma_f32_32x32x16_bf16(a1, b0, acc[1][0], 0, 0, 0);
            acc[1][1] = __builtin_amdgcn_mfma_f32_32x32x16_bf16(a1, b1, acc[1][1], 0, 0, 0);
        }
        __builtin_amdgcn_s_setprio(0);
        asm volatile("s_waitcnt lgkmcnt(0)" ::: "memory");   // my ds_reads retired
        __builtin_amdgcn_s_barrier();                        // barrier B: tile t consumed
        asm volatile("" ::: "memory");

        if (t + 1 < NT) stageB((t + 1) * 64);                // B(t+1) flies until next vmcnt
        kA0 = kB0; kA1 = kB1;
    }

    // ---- denominator: q = qq*32 + l31, partial per lane over its 16 u/tile ----
    dacc += __shfl_xor(dacc, 32);
    if (half == 0) denp[w][l31] = dacc;
    __syncthreads();
    if (tid < 128)
        rden[tid] = 1.0f / (denp[(tid >> 5) * 2][tid & 31] + denp[(tid >> 5) * 2 + 1][tid & 31]);
    __syncthreads();

#pragma unroll
    for (int at = 0; at < 2; ++at)
#pragma unroll
        for (int bt = 0; bt < 2; ++bt)
#pragma unroll
            for (int reg = 0; reg < 16; ++reg) {
                int lr = wm * 64 + at * 32 + (reg & 3) + 8 * (reg >> 2) + 4 * half;
                int e = ebase + wn * 64 + bt * 32 + l31;
                out[(size_t)(rowbase + lr) * DIM + e] = acc[at][bt][reg] * rden[lr];
            }
}

extern "C" void kernel_launch(void* const* d_in, const int* in_sizes, int n_in,
                              void* d_out, int out_size, void* d_ws, size_t ws_size,
                              hipStream_t stream) {
    const float* x  = (const float*)d_in[0];
    const float* Q  = (const float*)d_in[1];
    const float* K  = (const float*)d_in[2];
    const float* VO = (const float*)d_in[3];
    float* out = (float*)d_out;

    char* ws = (char*)d_ws;
    unsigned short* wqk  = (unsigned short*)(ws + 0);           // 64x1024 bf16        128 KB
    unsigned short* vot  = (unsigned short*)(ws + 131072);      // 1024x1024 bf16        2 MB
    unsigned short* xqk  = (unsigned short*)(ws + 2228224);     // 16384x64 bf16         2 MB
    unsigned short* xbf  = (unsigned short*)(ws + 4325376);     // 16384x1024 bf16      32 MB
    unsigned short* xvoT = (unsigned short*)(ws + 37879808);    // 4x1024x4096 bf16     32 MB

    k_cvt_qk<<<256, 256, 0, stream>>>(Q, K, wqk);
    k_transpose_cvt<<<dim3(16, 16, 1), 256, 0, stream>>>(VO, vot, 1024, 1024);
    k_xbf<<<8192, 256, 0, stream>>>(x, xbf);
    k_proj<<<128, 256, 0, stream>>>(xbf, wqk, xqk);
    k_xvo<<<dim3(16, 8, BATCH), 512, 0, stream>>>(vot, xbf, xvoT);
    k_spv<<<dim3(512, 1, 1), 512, 0, stream>>>(xqk, xvoT, out);
}